// Round 4
// baseline (192.278 us; speedup 1.0000x reference)
//
#include <hip/hip_runtime.h>

typedef _Float16 f16x8 __attribute__((ext_vector_type(8)));
typedef _Float16 f16x4 __attribute__((ext_vector_type(4)));
typedef float f32x4 __attribute__((ext_vector_type(4)));

#define NH 12
#define SEQ 2048
#define DM 768
#define DH 64
#define NROWS 49152  // 2*NH*SEQ

// ---------------- cast fp32 -> fp16 (X and the 4 weight matrices) --------
__global__ __launch_bounds__(256) void cast_kernel(
    const float* __restrict__ X, const float* __restrict__ Wq,
    const float* __restrict__ Wk, const float* __restrict__ Wv,
    const float* __restrict__ Wo, _Float16* __restrict__ Xh,
    _Float16* __restrict__ Wall)
{
    size_t base = ((size_t)blockIdx.x * 256 + threadIdx.x) * 8;
    const size_t NX = 3145728, NW = 589824, TOT = NX + 4 * NW;
    if (base >= TOT) return;
    const float* src;
    _Float16* dst;
    if (base < NX) { src = X + base; dst = Xh + base; }
    else {
        size_t r = base - NX;
        int w = (int)(r / NW);
        size_t o = r - (size_t)w * NW;
        src = (w == 0 ? Wq : w == 1 ? Wk : w == 2 ? Wv : Wo) + o;
        dst = Wall + r;
    }
    float4 a = *reinterpret_cast<const float4*>(src);
    float4 b = *reinterpret_cast<const float4*>(src + 4);
    f16x8 h;
    h[0] = (_Float16)a.x; h[1] = (_Float16)a.y; h[2] = (_Float16)a.z; h[3] = (_Float16)a.w;
    h[4] = (_Float16)b.x; h[5] = (_Float16)b.y; h[6] = (_Float16)b.z; h[7] = (_Float16)b.w;
    *reinterpret_cast<f16x8*>(dst) = h;
}

// ---------------- GEMM: out = A[4096x768] @ W^T + bias ------------------
// z=0 -> Q slab, z=1 -> K slab ([b,h,s,d]); z=2 -> V^T ([b,h,d,s]).
// is_out==1: fp32 d_out + bias.
__global__ __launch_bounds__(256) void gemm_kernel(
    const _Float16* __restrict__ A,
    const _Float16* __restrict__ Wbase,
    const float* __restrict__ b0, const float* __restrict__ b1,
    const float* __restrict__ b2,
    _Float16* __restrict__ outQKV, _Float16* __restrict__ outVT,
    float* __restrict__ outF32, int is_out)
{
    __shared__ _Float16 Asm[128 * 64];
    __shared__ _Float16 Bsm[128 * 64];
    const int tid = threadIdx.x;
    const int m0 = blockIdx.x * 128, n0 = blockIdx.y * 128, z = blockIdx.z;
    const _Float16* Wp = Wbase + (size_t)z * 589824;
    const float* bias = (z == 0) ? b0 : (z == 1 ? b1 : b2);
    const int w = tid >> 6, lane = tid & 63, lr = lane & 15, lg = lane >> 4;
    const int wm = w >> 1, wn = w & 1;

    f32x4 acc[4][4] = {};
    for (int kt = 0; kt < 12; ++kt) {
        __syncthreads();
        #pragma unroll
        for (int i = 0; i < 4; ++i) {
            int c = tid + i * 256;
            int row = c >> 3, col = (c & 7) * 8;
            int sw = (row & 7) << 4;
            f16x8 av = *reinterpret_cast<const f16x8*>(A + (size_t)(m0 + row) * 768 + kt * 64 + col);
            *reinterpret_cast<f16x8*>((char*)Asm + ((row * 128 + col * 2) ^ sw)) = av;
            f16x8 bv = *reinterpret_cast<const f16x8*>(Wp + (size_t)(n0 + row) * 768 + kt * 64 + col);
            *reinterpret_cast<f16x8*>((char*)Bsm + ((row * 128 + col * 2) ^ sw)) = bv;
        }
        __syncthreads();
        #pragma unroll
        for (int kf = 0; kf < 2; ++kf) {
            f16x8 af[4], bf[4];
            #pragma unroll
            for (int mi = 0; mi < 4; ++mi) {
                int row = wm * 64 + mi * 16 + lr;
                af[mi] = *reinterpret_cast<const f16x8*>(
                    (char*)Asm + ((row * 128 + kf * 64 + lg * 16) ^ ((row & 7) << 4)));
            }
            #pragma unroll
            for (int nj = 0; nj < 4; ++nj) {
                int row = wn * 64 + nj * 16 + lr;
                bf[nj] = *reinterpret_cast<const f16x8*>(
                    (char*)Bsm + ((row * 128 + kf * 64 + lg * 16) ^ ((row & 7) << 4)));
            }
            #pragma unroll
            for (int mi = 0; mi < 4; ++mi)
                #pragma unroll
                for (int nj = 0; nj < 4; ++nj)
                    acc[mi][nj] = __builtin_amdgcn_mfma_f32_16x16x32_f16(
                        af[mi], bf[nj], acc[mi][nj], 0, 0, 0);
        }
    }
    #pragma unroll
    for (int mi = 0; mi < 4; ++mi) {
        #pragma unroll
        for (int nj = 0; nj < 4; ++nj) {
            #pragma unroll
            for (int r = 0; r < 4; ++r) {
                int gm = m0 + wm * 64 + mi * 16 + lg * 4 + r;
                int gn = n0 + wn * 64 + nj * 16 + lr;
                float v = acc[mi][nj][r] + bias[gn];
                if (!is_out) {
                    int bb = gm >> 11, s = gm & 2047, hh = gn >> 6, dd = gn & 63;
                    if (z == 2)
                        outVT[(((size_t)bb * NH + hh) * DH + dd) * SEQ + s] = (_Float16)v;
                    else
                        outQKV[(size_t)z * 3145728 +
                               ((((size_t)bb * NH + hh) * SEQ + s) * DH + dd)] = (_Float16)v;
                } else {
                    outF32[(size_t)gm * 768 + gn] = v;
                }
            }
        }
    }
}

// ---------------- flash attention, swapped-QK^T + split-K ----------------
// Block = (b, h, 128 q-rows, ks half). 4 waves; wave w owns q-rows
// [w*32, w*32+32) = 2 q-frags. S computed as S[kt][q] (q = lane&15) so the
// softmax row is lane-local; P transposed to A-frag layout via vectorized
// LDS round-trip. V^T staged from transposed global layout (no transpose
// in-kernel). K-tile=64, 16 iterations.
__global__ __launch_bounds__(256, 3) void attn_kernel(
    const _Float16* __restrict__ Qh, const _Float16* __restrict__ Kh,
    const _Float16* __restrict__ VTg, const float* __restrict__ pb,
    const float* __restrict__ mask, _Float16* __restrict__ Opart,
    float* __restrict__ ml)
{
    __shared__ _Float16 Kl[64 * 64];      // [kt][d], XOR-swizzled (kt&7)<<4
    __shared__ _Float16 Vt[64 * 64];      // [d][kt], XOR-swizzled (d&7)<<4
    __shared__ _Float16 Pl[4 * 32 * 64];  // per-wave [q][kt], XOR-swizzled
    const int tid = threadIdx.x, w = tid >> 6, lane = tid & 63;
    const int lr = lane & 15, lg = lane >> 4;
    // XCD-aware decode: 768 blocks = 8 XCD * (3 bh * 16 q0 * 2 ks)
    const int lin = blockIdx.x;
    const int xcd = lin & 7, idx = lin >> 3;       // idx in [0,96)
    const int bh = xcd * 3 + idx / 32;
    const int rem = idx & 31;
    const int q0 = (rem >> 1) << 7;
    const int ks = rem & 1;
    const int kbase = ks << 10, kend = kbase + 1024;
    const int h = bh % NH, b = bh / NH;
    const size_t headoff = (size_t)bh * SEQ * DH;
    const _Float16* Qp = Qh + headoff;
    const _Float16* Kp = Kh + headoff;
    const _Float16* VTp = VTg + headoff;           // [d][s] per head
    const float L2E = 1.44269504f;

    // Q B-frags: lane lr = q-col within 16-block
    f16x8 qfr[2][2];
    #pragma unroll
    for (int qf = 0; qf < 2; ++qf)
        #pragma unroll
        for (int kf = 0; kf < 2; ++kf)
            qfr[qf][kf] = *reinterpret_cast<const f16x8*>(
                Qp + (size_t)(q0 + w * 32 + qf * 16 + lr) * DH + kf * 32 + lg * 8);

    const float* pbq[2];
    #pragma unroll
    for (int qf = 0; qf < 2; ++qf)
        pbq[qf] = pb + (size_t)h * SEQ * SEQ + (size_t)(q0 + w * 32 + qf * 16 + lr) * SEQ;
    const float* mrow = mask + (size_t)b * SEQ;

    f32x4 oacc[2][4] = {};
    float m_r[2] = {-3.0e38f, -3.0e38f}, l_r[2] = {0.f, 0.f};
    char* Pw = (char*)Pl + w * 4096;
    char* KlB = (char*)Kl;
    char* VtB = (char*)Vt;

    const int c0 = tid, c1 = tid + 256;
    const int row0 = c0 >> 3, col0 = (c0 & 7) << 3;
    const int row1 = c1 >> 3, col1 = (c1 & 7) << 3;
    f16x8 kn[2], vn[2];

    // prologue: tile kbase into regs -> LDS; pb tile into regs
    kn[0] = *reinterpret_cast<const f16x8*>(Kp + (size_t)(kbase + row0) * DH + col0);
    kn[1] = *reinterpret_cast<const f16x8*>(Kp + (size_t)(kbase + row1) * DH + col1);
    vn[0] = *reinterpret_cast<const f16x8*>(VTp + (size_t)row0 * SEQ + kbase + col0);
    vn[1] = *reinterpret_cast<const f16x8*>(VTp + (size_t)row1 * SEQ + kbase + col1);
    f32x4 pbc[2][4];
    #pragma unroll
    for (int cf = 0; cf < 4; ++cf) {
        f32x4 mk = *reinterpret_cast<const f32x4*>(mrow + kbase + cf * 16 + lg * 4);
        #pragma unroll
        for (int qf = 0; qf < 2; ++qf)
            pbc[qf][cf] = (*reinterpret_cast<const f32x4*>(pbq[qf] + kbase + cf * 16 + lg * 4) + mk) * L2E;
    }
    *reinterpret_cast<f16x8*>(KlB + ((row0 * 128 + col0 * 2) ^ ((row0 & 7) << 4))) = kn[0];
    *reinterpret_cast<f16x8*>(KlB + ((row1 * 128 + col1 * 2) ^ ((row1 & 7) << 4))) = kn[1];
    *reinterpret_cast<f16x8*>(VtB + ((row0 * 128 + col0 * 2) ^ ((row0 & 7) << 4))) = vn[0];
    *reinterpret_cast<f16x8*>(VtB + ((row1 * 128 + col1 * 2) ^ ((row1 & 7) << 4))) = vn[1];
    __syncthreads();

    for (int kt0 = kbase; kt0 < kend; kt0 += 64) {
        const int nt = (kt0 + 64 < kend) ? kt0 + 64 : kt0;
        // issue next K/V tile loads (hidden under this tile's compute)
        kn[0] = *reinterpret_cast<const f16x8*>(Kp + (size_t)(nt + row0) * DH + col0);
        kn[1] = *reinterpret_cast<const f16x8*>(Kp + (size_t)(nt + row1) * DH + col1);
        vn[0] = *reinterpret_cast<const f16x8*>(VTp + (size_t)row0 * SEQ + nt + col0);
        vn[1] = *reinterpret_cast<const f16x8*>(VTp + (size_t)row1 * SEQ + nt + col1);

        // ---- QK^T swapped: S[kt][q], K-frags reused across both q-frags --
        f32x4 sc[2][4] = {};
        #pragma unroll
        for (int cf = 0; cf < 4; ++cf) {
            #pragma unroll
            for (int kf = 0; kf < 2; ++kf) {
                f16x8 ka = *reinterpret_cast<const f16x8*>(
                    KlB + (((cf * 16 + lr) * 128 + kf * 64 + lg * 16) ^ ((lr & 7) << 4)));
                #pragma unroll
                for (int qf = 0; qf < 2; ++qf)
                    sc[qf][cf] = __builtin_amdgcn_mfma_f32_16x16x32_f16(
                        ka, qfr[qf][kf], sc[qf][cf], 0, 0, 0);
            }
        }
        // sv = sc*scale + (pb+mask)*log2e  (in-place)
        #pragma unroll
        for (int qf = 0; qf < 2; ++qf)
            #pragma unroll
            for (int cf = 0; cf < 4; ++cf)
                sc[qf][cf] = sc[qf][cf] * 0.18033688f + pbc[qf][cf];

        // issue next pb loads into the just-consumed registers
        #pragma unroll
        for (int cf = 0; cf < 4; ++cf) {
            f32x4 mk = *reinterpret_cast<const f32x4*>(mrow + nt + cf * 16 + lg * 4);
            #pragma unroll
            for (int qf = 0; qf < 2; ++qf)
                pbc[qf][cf] = (*reinterpret_cast<const f32x4*>(pbq[qf] + nt + cf * 16 + lg * 4) + mk) * L2E;
        }

        // ---- online softmax: row q = lr is lane-local over 16 kt values --
        #pragma unroll
        for (int qf = 0; qf < 2; ++qf) {
            float t = sc[qf][0][0];
            #pragma unroll
            for (int cf = 0; cf < 4; ++cf)
                #pragma unroll
                for (int r = 0; r < 4; ++r) t = fmaxf(t, sc[qf][cf][r]);
            t = fmaxf(t, __shfl_xor(t, 16));
            t = fmaxf(t, __shfl_xor(t, 32));
            float mn = fmaxf(m_r[qf], t);
            float srow = exp2f(m_r[qf] - mn);
            m_r[qf] = mn;
            float rs = 0.f;
            const int qrow = qf * 16 + lr;
            #pragma unroll
            for (int cf = 0; cf < 4; ++cf) {
                f16x4 pv;
                #pragma unroll
                for (int r = 0; r < 4; ++r) {
                    float p = exp2f(sc[qf][cf][r] - mn);
                    rs += p;
                    pv[r] = (_Float16)p;
                }
                *reinterpret_cast<f16x4*>(
                    Pw + ((qrow * 128 + cf * 32 + lg * 8) ^ ((lr & 7) << 4))) = pv;
            }
            rs += __shfl_xor(rs, 16);
            rs += __shfl_xor(rs, 32);
            l_r[qf] = l_r[qf] * srow + rs;
            // transpose the rescale factor into O-accumulator row layout
            float s0 = __shfl(srow, lg * 4 + 0);
            float s1 = __shfl(srow, lg * 4 + 1);
            float s2 = __shfl(srow, lg * 4 + 2);
            float s3 = __shfl(srow, lg * 4 + 3);
            f32x4 scv = {s0, s1, s2, s3};
            #pragma unroll
            for (int cf = 0; cf < 4; ++cf) oacc[qf][cf] *= scv;
        }

        // ---- PV: A = P (LDS round-trip), B = V^T frags (shared) ----------
        #pragma unroll
        for (int kf = 0; kf < 2; ++kf) {
            f16x8 pa0 = *reinterpret_cast<const f16x8*>(
                Pw + ((lr * 128 + kf * 64 + lg * 16) ^ ((lr & 7) << 4)));
            f16x8 pa1 = *reinterpret_cast<const f16x8*>(
                Pw + (((16 + lr) * 128 + kf * 64 + lg * 16) ^ ((lr & 7) << 4)));
            #pragma unroll
            for (int cf = 0; cf < 4; ++cf) {
                f16x8 vb = *reinterpret_cast<const f16x8*>(
                    VtB + (((cf * 16 + lr) * 128 + kf * 64 + lg * 16) ^ ((lr & 7) << 4)));
                oacc[0][cf] = __builtin_amdgcn_mfma_f32_16x16x32_f16(pa0, vb, oacc[0][cf], 0, 0, 0);
                oacc[1][cf] = __builtin_amdgcn_mfma_f32_16x16x32_f16(pa1, vb, oacc[1][cf], 0, 0, 0);
            }
        }

        // ---- commit prefetched tile ----
        __syncthreads();
        *reinterpret_cast<f16x8*>(KlB + ((row0 * 128 + col0 * 2) ^ ((row0 & 7) << 4))) = kn[0];
        *reinterpret_cast<f16x8*>(KlB + ((row1 * 128 + col1 * 2) ^ ((row1 & 7) << 4))) = kn[1];
        *reinterpret_cast<f16x8*>(VtB + ((row0 * 128 + col0 * 2) ^ ((row0 & 7) << 4))) = vn[0];
        *reinterpret_cast<f16x8*>(VtB + ((row1 * 128 + col1 * 2) ^ ((row1 & 7) << 4))) = vn[1];
        __syncthreads();
    }

    // epilogue: unnormalized O (fp16) + (m,l) per row
    #pragma unroll
    for (int qf = 0; qf < 2; ++qf) {
        size_t rowbase = (size_t)bh * SEQ + q0 + w * 32 + qf * 16;
        if (lane < 16) {
            size_t rowi = rowbase + lr;
            ml[rowi * 4 + ks * 2 + 0] = m_r[qf];
            ml[rowi * 4 + ks * 2 + 1] = l_r[qf];
        }
        #pragma unroll
        for (int r = 0; r < 4; ++r) {
            size_t rowi = rowbase + lg * 4 + r;
            _Float16* od = Opart + ((size_t)ks * NROWS + rowi) * DH;
            #pragma unroll
            for (int cf = 0; cf < 4; ++cf)
                od[cf * 16 + lr] = (_Float16)oacc[qf][cf][r];
        }
    }
}

// ---------------- merge the two split-K partials -------------------------
__global__ __launch_bounds__(256) void merge_kernel(
    const _Float16* __restrict__ Opart, const float* __restrict__ ml,
    _Float16* __restrict__ ctx)
{
    int gid = blockIdx.x * 256 + threadIdx.x;      // 49152*8 threads
    int row = gid >> 3, d8 = (gid & 7) << 3;
    const size_t NP = (size_t)NROWS * DH;
    f16x8 o0 = *reinterpret_cast<const f16x8*>(Opart + (size_t)row * DH + d8);
    f16x8 o1 = *reinterpret_cast<const f16x8*>(Opart + NP + (size_t)row * DH + d8);
    float4 m = *reinterpret_cast<const float4*>(ml + (size_t)row * 4);
    float M = fmaxf(m.x, m.z);
    float a0 = exp2f(m.x - M), a1 = exp2f(m.z - M);
    float inv = 1.0f / (a0 * m.y + a1 * m.w);
    a0 *= inv; a1 *= inv;
    f16x8 o;
    #pragma unroll
    for (int j = 0; j < 8; ++j)
        o[j] = (_Float16)(a0 * (float)o0[j] + a1 * (float)o1[j]);
    int b = row / (NH * SEQ);
    int hs = row - b * (NH * SEQ);
    int h = hs >> 11, s = hs & 2047;
    *reinterpret_cast<f16x8*>(ctx + ((size_t)b * SEQ + s) * DM + h * DH + d8) = o;
}

extern "C" void kernel_launch(void* const* d_in, const int* in_sizes, int n_in,
                              void* d_out, int out_size, void* d_ws, size_t ws_size,
                              hipStream_t stream) {
    const float* X    = (const float*)d_in[0];
    const float* mask = (const float*)d_in[1];
    const float* pb   = (const float*)d_in[2];
    const float* Wq   = (const float*)d_in[3];
    const float* bq   = (const float*)d_in[4];
    const float* Wk   = (const float*)d_in[5];
    const float* bk   = (const float*)d_in[6];
    const float* Wv   = (const float*)d_in[7];
    const float* bv   = (const float*)d_in[8];
    const float* Wo   = (const float*)d_in[9];
    const float* bo   = (const float*)d_in[10];
    float* out = (float*)d_out;

    _Float16* Xh    = (_Float16*)d_ws;              // 3145728 f16
    _Float16* Wall  = Xh + 3145728;                 // 4 * 589824 f16
    _Float16* QK    = Wall + 4 * 589824;            // Q,K slabs: 2 * 3145728
    _Float16* VT    = QK + 2 * 3145728;             // V^T: 3145728
    _Float16* ctx   = VT + 3145728;                 // 3145728
    _Float16* Opart = ctx + 3145728;                // 2 * 3145728
    float*    ml    = (float*)(Opart + 2 * 3145728); // 49152*4 f32

    cast_kernel<<<2688, 256, 0, stream>>>(X, Wq, Wk, Wv, Wo, Xh, Wall);
    gemm_kernel<<<dim3(32, 6, 3), 256, 0, stream>>>(
        Xh, Wall, bq, bk, bv, QK, VT, nullptr, 0);
    attn_kernel<<<768, 256, 0, stream>>>(
        QK, QK + 3145728, VT, pb, mask, Opart, ml);
    merge_kernel<<<1536, 256, 0, stream>>>(Opart, ml, ctx);
    gemm_kernel<<<dim3(32, 6, 1), 256, 0, stream>>>(
        ctx, Wall + 3 * 589824, bo, bo, bo, nullptr, nullptr, out, 1);
}